// Round 3
// baseline (439.163 us; speedup 1.0000x reference)
//
#include <hip/hip_runtime.h>
#include <hip/hip_bf16.h>

typedef short  short8  __attribute__((ext_vector_type(8)));
typedef float  f32x16  __attribute__((ext_vector_type(16)));
typedef unsigned short ushort_t;

#define B_    8
#define CIN_  64
#define COUT_ 64
#define MID_  64
#define HH    256
#define WW    256
#define NP_   4
#define NL_   5

#define TR 8              // output rows per block strip
#define TC 32             // output cols per tile
#define NJT 8             // 8*32 = 256 exact
#define SR 10             // slab rows (TR + 2 halo)
#define SCC 34            // slab cols (TC + 2 halo)
#define SLAB_U32 (SR*8*SCC*4)   // 10880 u32 = 43520 B
#define W_SHORTS (9*8*COUT_*8)  // 36864 shorts in wsW per batch
#define WL_SHORTS (9*8*32*8)    // 18432 shorts staged (half the cout) = 36864 B
#define NSTG 22                 // ceil(10880/512)

// ---------------- Kernel 1: hypernet -> combined bf16 weights ----------------
// wsW layout: [b][khkw][ci>>3][co][ci&7] shorts (verified)
__global__ __launch_bounds__(256)
void build_weights(const float* __restrict__ h, const float* __restrict__ index,
                   const float* __restrict__ conv_weight,
                   const float* __restrict__ W_wp, const float* __restrict__ b_wp,
                   const float* __restrict__ W_wi, const float* __restrict__ b_wi,
                   const float* __restrict__ W_we, const float* __restrict__ b_we,
                   ushort_t* __restrict__ wsW) {
    const int bb  = blockIdx.x / 9;       // batch
    const int ch  = blockIdx.x - bb * 9;  // o9 chunk of 64
    const int tid = threadIdx.x;

    __shared__ float pre_s[64 * 66];      // padded stride 66
    __shared__ float chunk_s[64 * 64];    // W_we chunk: 64 o9 x 64 mid

    float hv[NP_], iv[NL_];
#pragma unroll
    for (int p = 0; p < NP_; ++p) hv[p] = h[bb * NP_ + p];
#pragma unroll
    for (int l = 0; l < NL_; ++l) iv[l] = index[l];

#pragma unroll
    for (int k = 0; k < 16; ++k) {
        const int m = tid + k * 256;
        float a = b_wp[m] + b_wi[m];
#pragma unroll
        for (int p = 0; p < NP_; ++p) a += hv[p] * W_wp[m * NP_ + p];
#pragma unroll
        for (int l = 0; l < NL_; ++l) a += iv[l] * W_wi[m * NL_ + l];
        pre_s[(m >> 6) * 66 + (m & 63)] = a;
    }
#pragma unroll
    for (int k = 0; k < 16; ++k) {
        const int f = tid + k * 256;
        chunk_s[f] = W_we[ch * 4096 + f];
    }
    __syncthreads();

    const int ci = tid & 63;
    const int g  = tid >> 6;   // 0..3, uniform per wave -> chunk reads broadcast
    float acc[16];
#pragma unroll
    for (int u = 0; u < 16; ++u) acc[u] = 0.f;

#pragma unroll
    for (int mid = 0; mid < 64; mid += 2) {
        const float2 pv = *(const float2*)&pre_s[ci * 66 + mid];
#pragma unroll
        for (int u = 0; u < 16; ++u) {
            const float2 wv = *(const float2*)&chunk_s[(g + 4 * u) * 64 + mid];
            acc[u] += pv.x * wv.x + pv.y * wv.y;
        }
    }

#pragma unroll
    for (int u = 0; u < 16; ++u) {
        const int o9 = ch * 64 + g + 4 * u;
        const int co = o9 / 9;
        const int r  = o9 - co * 9;
        const float val = acc[u] + b_we[o9] + conv_weight[(co * CIN_ + ci) * 9 + r];
        __hip_bfloat16 hb = __float2bfloat16(val);
        ushort_t bits; __builtin_memcpy(&bits, &hb, 2);
        wsW[(((bb * 9 + r) * 8 + (ci >> 3)) * COUT_ + co) * 8 + (ci & 7)] = bits;
    }
}

// ---------------- Kernel 2: MFMA implicit-GEMM conv (half-cout blocks) ----------
// Slab layout (u32, each = bf16 ci-pair): [r 10][g 8][c 34][p 4], ci = g*8 + 2p (+0/1)
// Round-0 verified load path: convert at load, __syncthreads structure.
__device__ __forceinline__ void load_tile(const float* __restrict__ xb, int i0, int j0,
                                          int tid, unsigned (&vals)[NSTG]) {
#pragma unroll
    for (int k = 0; k < NSTG; ++k) {
        const int s = tid + k * 512;
        unsigned v = 0u;
        if (s < SLAB_U32) {
            const int p  = s & 3;
            const int t2 = s >> 2;
            const int c  = t2 % SCC;
            const int t3 = t2 / SCC;      // r*8 + g
            const int g  = t3 & 7;
            const int r  = t3 >> 3;
            const int gr = i0 - 1 + r;
            const int gc = j0 - 1 + c;
            const int ci = g * 8 + p * 2;
            const bool ok = ((unsigned)gr < (unsigned)HH) && ((unsigned)gc < (unsigned)WW);
            const float* px = xb + ci * (HH * WW) + (ok ? (gr * WW + gc) : 0);
            float f0 = px[0];
            float f1 = px[HH * WW];
            if (!ok) { f0 = 0.f; f1 = 0.f; }
            const __hip_bfloat162 h2 = __float22bfloat162_rn(make_float2(f0, f1));
            __builtin_memcpy(&v, &h2, 4);
        }
        vals[k] = v;
    }
}

__global__ __launch_bounds__(512, 4)
void hyperconv(const float* __restrict__ x, const ushort_t* __restrict__ wsW,
               const float* __restrict__ conv_bias,
               const float* __restrict__ h, const float* __restrict__ index,
               const float* __restrict__ W_bp, const float* __restrict__ b_bp,
               const float* __restrict__ W_bi, const float* __restrict__ b_bi,
               float* __restrict__ out) {
    __shared__ __align__(16) ushort_t Wl[WL_SHORTS];  // 36864 B (half the cout)
    __shared__ __align__(16) unsigned Slab[SLAB_U32]; // 43520 B
    __shared__ float biasl[32];
    // total LDS = 80512 B  ->  2 blocks/CU

    const int tid  = threadIdx.x;
    const int p    = blockIdx.x;
    // Pairing decode: blocks p and p+256 are the two cout-halves of the same
    // strip and land on the same XCD under round-robin dispatch -> the second
    // half's x-slab reads hit that XCD's L2.
    const int half  = p >> 8;        // 0..1  (cout half)
    const int rest  = p & 255;
    const int bb    = rest & 7;      // batch  (== XCD under %8 round-robin)
    const int strip = rest >> 3;     // 0..31
    const int i0    = strip * TR;
    const float* xb = x + bb * CIN_ * HH * WW;

    // prefetch tile 0 into regs first (latency hidden under Wl/bias setup)
    unsigned vals[NSTG];
    load_tile(xb, i0, 0, tid, vals);

    // stage this half's weights: 72 rows x 32 co x 8 shorts (row src stride = 64 co)
    {
        const uint4* src = (const uint4*)(wsW + bb * W_SHORTS);  // 64 u4 per row
        uint4* dst = (uint4*)Wl;                                 // 32 u4 per row
#pragma unroll
        for (int k = 0; k < 5; ++k) {
            const int idx = tid + k * 512;          // 0..2303
            if (idx < (WL_SHORTS / 8)) {
                const int row = idx >> 5;           // gA row 0..71
                const int off = idx & 31;
                dst[idx] = src[row * 64 + half * 32 + off];
            }
        }
    }
    // per-sample bias for this half
    if (tid < 32) {
        const int co = half * 32 + tid;
        float a = conv_bias[co] + b_bp[co] + b_bi[co];
#pragma unroll
        for (int q = 0; q < NP_; ++q) a += h[bb * NP_ + q] * W_bp[co * NP_ + q];
#pragma unroll
        for (int l = 0; l < NL_; ++l) a += index[l] * W_bi[co * NL_ + l];
        biasl[tid] = a;
    }

    const int lane = tid & 63;
    const int wv   = tid >> 6;     // 0..7 -> output row within strip
    const int n    = lane & 31;    // output col within tile / co-in-half for A
    const int hl   = lane >> 5;    // k-half

    for (int jt = 0; jt < NJT; ++jt) {
        __syncthreads();   // iter 0: Wl/bias ready; later: prior slab reads done
        // write current tile regs -> slab (waits the global loads here)
#pragma unroll
        for (int k = 0; k < NSTG; ++k) {
            const int s = tid + k * 512;
            if (s < SLAB_U32) Slab[s] = vals[k];
        }
        // issue next tile's loads (drain at NEXT iteration's first barrier)
        if (jt + 1 < NJT) load_tile(xb, i0, (jt + 1) * TC, tid, vals);
        __syncthreads();   // slab visible

        f32x16 a0 = {};
        const ushort_t* sl = (const ushort_t*)Slab;
#pragma unroll
        for (int kh = 0; kh < 3; ++kh)
#pragma unroll
            for (int kw = 0; kw < 3; ++kw) {
                const int khkw = kh * 3 + kw;
#pragma unroll
                for (int kk = 0; kk < 4; ++kk) {
                    const int gA = khkw * 8 + 2 * kk + hl;
                    const short8 A0 = *(const short8*)&Wl[(gA * 32 + n) * 8];
                    const int gB = ((wv + kh) * 8 + 2 * kk + hl) * SCC + (n + kw);
                    const short8 Bf = *(const short8*)&sl[gB * 8];
                    a0 = __builtin_amdgcn_mfma_f32_32x32x16_bf16(A0, Bf, a0, 0, 0, 0);
                }
            }

        // epilogue: line-aligned stores (32 cout planes for this half)
        const int j0 = jt * TC;
        float* op = out + (size_t)(bb * COUT_ + half * 32) * (HH * WW)
                  + (i0 + wv) * WW + j0 + n;
#pragma unroll
        for (int r = 0; r < 16; ++r) {
            const int col = (r & 3) + 8 * (r >> 2) + 4 * hl;   // 0..31 within half
            op[col * (HH * WW)] = a0[r] + biasl[col];
        }
    }
}

extern "C" void kernel_launch(void* const* d_in, const int* in_sizes, int n_in,
                              void* d_out, int out_size, void* d_ws, size_t ws_size,
                              hipStream_t stream) {
    const float* x           = (const float*)d_in[0];
    const float* h           = (const float*)d_in[1];
    const float* index       = (const float*)d_in[2];
    const float* conv_weight = (const float*)d_in[3];
    const float* conv_bias   = (const float*)d_in[4];
    const float* W_wp        = (const float*)d_in[5];
    const float* b_wp        = (const float*)d_in[6];
    const float* W_wi        = (const float*)d_in[7];
    const float* b_wi        = (const float*)d_in[8];
    const float* W_we        = (const float*)d_in[9];
    const float* b_we        = (const float*)d_in[10];
    const float* W_bp        = (const float*)d_in[11];
    const float* b_bp        = (const float*)d_in[12];
    const float* W_bi        = (const float*)d_in[13];
    const float* b_bi        = (const float*)d_in[14];

    float* out = (float*)d_out;
    ushort_t* wsW = (ushort_t*)d_ws;   // 8 * 36864 * 2 = 589824 B

    build_weights<<<72, 256, 0, stream>>>(
        h, index, conv_weight, W_wp, b_wp, W_wi, b_wi, W_we, b_we, wsW);

    hyperconv<<<512, 512, 0, stream>>>(
        x, wsW, conv_bias, h, index, W_bp, b_bp, W_bi, b_bi, out);
}

// Round 4
// 347.461 us; speedup vs baseline: 1.2639x; 1.2639x over previous
//
#include <hip/hip_runtime.h>
#include <hip/hip_bf16.h>

typedef short  short8  __attribute__((ext_vector_type(8)));
typedef float  f32x16  __attribute__((ext_vector_type(16)));
typedef unsigned short ushort_t;

#define B_    8
#define CIN_  64
#define COUT_ 64
#define MID_  64
#define HH    256
#define WW    256
#define NP_   4
#define NL_   5

#define TR 8              // output rows per block strip
#define TC 32             // output cols per tile
#define NJT 8             // 8*32 = 256 exact
#define SR 10             // slab rows (TR + 2 halo)
#define SCC 34            // slab cols (TC + 2 halo)
#define SLAB_U32 (SR*8*SCC*4)   // 10880 u32 = 43520 B
#define W_SHORTS (9*8*COUT_*8)  // 36864 shorts = 73728 B
#define NSTG 22                 // ceil(10880/512)

// ---------------- Kernel 1: hypernet -> combined bf16 weights ----------------
// wsW layout: [b][khkw][ci>>3][co][ci&7] shorts (verified)
__global__ __launch_bounds__(256)
void build_weights(const float* __restrict__ h, const float* __restrict__ index,
                   const float* __restrict__ conv_weight,
                   const float* __restrict__ W_wp, const float* __restrict__ b_wp,
                   const float* __restrict__ W_wi, const float* __restrict__ b_wi,
                   const float* __restrict__ W_we, const float* __restrict__ b_we,
                   ushort_t* __restrict__ wsW) {
    const int bb  = blockIdx.x / 9;       // batch
    const int ch  = blockIdx.x - bb * 9;  // o9 chunk of 64
    const int tid = threadIdx.x;

    __shared__ float pre_s[64 * 66];      // padded stride 66
    __shared__ float chunk_s[64 * 64];    // W_we chunk: 64 o9 x 64 mid

    float hv[NP_], iv[NL_];
#pragma unroll
    for (int p = 0; p < NP_; ++p) hv[p] = h[bb * NP_ + p];
#pragma unroll
    for (int l = 0; l < NL_; ++l) iv[l] = index[l];

#pragma unroll
    for (int k = 0; k < 16; ++k) {
        const int m = tid + k * 256;
        float a = b_wp[m] + b_wi[m];
#pragma unroll
        for (int p = 0; p < NP_; ++p) a += hv[p] * W_wp[m * NP_ + p];
#pragma unroll
        for (int l = 0; l < NL_; ++l) a += iv[l] * W_wi[m * NL_ + l];
        pre_s[(m >> 6) * 66 + (m & 63)] = a;
    }
#pragma unroll
    for (int k = 0; k < 16; ++k) {
        const int f = tid + k * 256;
        chunk_s[f] = W_we[ch * 4096 + f];
    }
    __syncthreads();

    const int ci = tid & 63;
    const int g  = tid >> 6;   // 0..3, uniform per wave -> chunk reads broadcast
    float acc[16];
#pragma unroll
    for (int u = 0; u < 16; ++u) acc[u] = 0.f;

#pragma unroll
    for (int mid = 0; mid < 64; mid += 2) {
        const float2 pv = *(const float2*)&pre_s[ci * 66 + mid];
#pragma unroll
        for (int u = 0; u < 16; ++u) {
            const float2 wv = *(const float2*)&chunk_s[(g + 4 * u) * 64 + mid];
            acc[u] += pv.x * wv.x + pv.y * wv.y;
        }
    }

#pragma unroll
    for (int u = 0; u < 16; ++u) {
        const int o9 = ch * 64 + g + 4 * u;
        const int co = o9 / 9;
        const int r  = o9 - co * 9;
        const float val = acc[u] + b_we[o9] + conv_weight[(co * CIN_ + ci) * 9 + r];
        __hip_bfloat16 hb = __float2bfloat16(val);
        ushort_t bits; __builtin_memcpy(&bits, &hb, 2);
        wsW[(((bb * 9 + r) * 8 + (ci >> 3)) * COUT_ + co) * 8 + (ci & 7)] = bits;
    }
}

// ---------------- Kernel 2: MFMA implicit-GEMM conv ----------------
// Slab layout (u32, each = bf16 ci-pair): [r 10][g 8][c 34][p 4], ci = g*8 + 2p (+0/1)
// Split staging: RAW scalar loads (no cvt at issue -> no vmcnt waits in load phase),
// convert+mask next iter during slab write; barriers never drain vmcnt.

__device__ __forceinline__ void load_raw(const float* __restrict__ xb,
                                         const int (&rel)[NSTG], int j0,
                                         bool eLo, bool eHi,
                                         unsigned m0, unsigned m7,
                                         float (&f0)[NSTG], float (&f1)[NSTG]) {
#pragma unroll
    for (int k = 0; k < NSTG; ++k) {
        int off = rel[k] + j0;
        if (eLo) off += (int)((m0 >> k) & 1u);   // gc=-1  -> clamp to 0
        if (eHi) off -= (int)((m7 >> k) & 1u);   // gc=256 -> clamp to 255
        const float* px = xb + off;
        f0[k] = px[0];
        f1[k] = px[HH * WW];
    }
}

__global__ __launch_bounds__(512, 2)
void hyperconv(const float* __restrict__ x, const ushort_t* __restrict__ wsW,
               const float* __restrict__ conv_bias,
               const float* __restrict__ h, const float* __restrict__ index,
               const float* __restrict__ W_bp, const float* __restrict__ b_bp,
               const float* __restrict__ W_bi, const float* __restrict__ b_bi,
               float* __restrict__ out) {
    __shared__ __align__(16) ushort_t Wl[W_SHORTS];   // 73728 B
    __shared__ __align__(16) unsigned Slab[SLAB_U32]; // 43520 B
    __shared__ float biasl[COUT_];

    const int tid   = threadIdx.x;
    const int bb    = blockIdx.x >> 5;
    const int strip = blockIdx.x & 31;
    const int i0    = strip * TR;
    const float* xb = x + bb * CIN_ * HH * WW;

    // ---- static per-unit descriptors (round-0 decode, hoisted out of the loop) ----
    int rel[NSTG];
    unsigned vmask = 0u, m0 = 0u, m7 = 0u;
#pragma unroll
    for (int k = 0; k < NSTG; ++k) {
        const int s  = tid + k * 512;
        const int p  = s & 3;
        const int t2 = s >> 2;
        const int c  = t2 % SCC;
        const int t3 = t2 / SCC;      // r*8 + g
        const int g  = t3 & 7;
        const int r  = t3 >> 3;
        const int gr  = i0 - 1 + r;
        const int grc = gr < 0 ? 0 : (gr > HH - 1 ? HH - 1 : gr);
        const int ci  = g * 8 + p * 2;
        rel[k] = ci * (HH * WW) + grc * WW + (c - 1);
        if ((s < SLAB_U32) && ((unsigned)gr < (unsigned)HH)) vmask |= 1u << k;
        if (c == 0)       m0 |= 1u << k;
        if (c == SCC - 1) m7 |= 1u << k;
    }

    // ---- prefetch tile 0 raw (stays in flight through prologue) ----
    float f0[NSTG], f1[NSTG];
    load_raw(xb, rel, 0, true, false, m0, m7, f0, f1);

    // ---- stage weights (coalesced 16B; L2/L3-resident) ----
    {
        const uint4* src = (const uint4*)(wsW + bb * W_SHORTS);
        uint4* dst = (uint4*)Wl;
#pragma unroll
        for (int i = 0; i < (W_SHORTS / 8) / 512; ++i)   // 9 exact
            dst[tid + i * 512] = src[tid + i * 512];
    }
    // ---- per-sample bias ----
    if (tid < COUT_) {
        const int co = tid;
        float a = conv_bias[co] + b_bp[co] + b_bi[co];
#pragma unroll
        for (int p = 0; p < NP_; ++p) a += h[bb * NP_ + p] * W_bp[co * NP_ + p];
#pragma unroll
        for (int l = 0; l < NL_; ++l) a += index[l] * W_bi[co * NL_ + l];
        biasl[co] = a;
    }

    const int lane = tid & 63;
    const int wv   = tid >> 6;     // 0..7 -> output row within strip
    const int n    = lane & 31;    // output col within tile / co for A
    const int hl   = lane >> 5;    // k-half

#pragma unroll 1
    for (int jt = 0; jt < NJT; ++jt) {
        // top barrier: prior-iter slab reads all retired (data-dep through MFMA->stores).
        // Does NOT drain vmcnt -> prefetched loads keep draining.
        asm volatile("" ::: "memory");
        __builtin_amdgcn_s_barrier();
        asm volatile("" ::: "memory");

        // convert current tile regs -> slab. Compiler emits progressive vmcnt(N)
        // waits here (oldest=these loads; epilogue stores are newer -> never waited).
        const unsigned wmask = (jt == 0)       ? (vmask & ~m0)
                             : (jt == NJT - 1) ? (vmask & ~m7) : vmask;
#pragma unroll
        for (int k = 0; k < NSTG; ++k) {
            const int s = tid + k * 512;
            if (s < SLAB_U32) {
                const __hip_bfloat162 h2 =
                    __float22bfloat162_rn(make_float2(f0[k], f1[k]));
                unsigned v; __builtin_memcpy(&v, &h2, 4);
                v = ((wmask >> k) & 1u) ? v : 0u;
                Slab[s] = v;
            }
        }

        // issue next tile's raw loads (nothing consumes them -> no waits emitted)
        if (jt + 1 < NJT)
            load_raw(xb, rel, (jt + 1) * TC, false, (jt + 1 == NJT - 1), m0, m7, f0, f1);

        // own LDS writes committed -> barrier: slab visible. vmcnt NOT drained.
        asm volatile("s_waitcnt lgkmcnt(0)" ::: "memory");
        __builtin_amdgcn_s_barrier();
        asm volatile("" ::: "memory");

        f32x16 a0 = {}, a1 = {};
        const ushort_t* sl = (const ushort_t*)Slab;
#pragma unroll
        for (int kh = 0; kh < 3; ++kh)
#pragma unroll
            for (int kw = 0; kw < 3; ++kw) {
                const int khkw = kh * 3 + kw;
#pragma unroll
                for (int kk = 0; kk < 4; ++kk) {
                    const int gA = khkw * 8 + 2 * kk + hl;
                    const short8 A0 = *(const short8*)&Wl[(gA * 64 + n) * 8];
                    const short8 A1 = *(const short8*)&Wl[(gA * 64 + n + 32) * 8];
                    const int gB = ((wv + kh) * 8 + 2 * kk + hl) * SCC + (n + kw);
                    const short8 Bf = *(const short8*)&sl[gB * 8];
                    a0 = __builtin_amdgcn_mfma_f32_32x32x16_bf16(A0, Bf, a0, 0, 0, 0);
                    a1 = __builtin_amdgcn_mfma_f32_32x32x16_bf16(A1, Bf, a1, 0, 0, 0);
                }
            }

        // epilogue: fully line-aligned stores (fire-and-forget; drain across iters)
        const int j0 = jt * TC;
        float* op = out + (size_t)(bb * COUT_) * (HH * WW) + (i0 + wv) * WW + j0 + n;
#pragma unroll
        for (int r = 0; r < 16; ++r) {
            const int co = (r & 3) + 8 * (r >> 2) + 4 * hl;
            op[co * (HH * WW)] = a0[r] + biasl[co];
        }
#pragma unroll
        for (int r = 0; r < 16; ++r) {
            const int co = (r & 3) + 8 * (r >> 2) + 4 * hl + 32;
            op[co * (HH * WW)] = a1[r] + biasl[co];
        }
    }
}

extern "C" void kernel_launch(void* const* d_in, const int* in_sizes, int n_in,
                              void* d_out, int out_size, void* d_ws, size_t ws_size,
                              hipStream_t stream) {
    const float* x           = (const float*)d_in[0];
    const float* h           = (const float*)d_in[1];
    const float* index       = (const float*)d_in[2];
    const float* conv_weight = (const float*)d_in[3];
    const float* conv_bias   = (const float*)d_in[4];
    const float* W_wp        = (const float*)d_in[5];
    const float* b_wp        = (const float*)d_in[6];
    const float* W_wi        = (const float*)d_in[7];
    const float* b_wi        = (const float*)d_in[8];
    const float* W_we        = (const float*)d_in[9];
    const float* b_we        = (const float*)d_in[10];
    const float* W_bp        = (const float*)d_in[11];
    const float* b_bp        = (const float*)d_in[12];
    const float* W_bi        = (const float*)d_in[13];
    const float* b_bi        = (const float*)d_in[14];

    float* out = (float*)d_out;
    ushort_t* wsW = (ushort_t*)d_ws;   // 8 * 36864 * 2 = 589824 B

    build_weights<<<72, 256, 0, stream>>>(
        h, index, conv_weight, W_wp, b_wp, W_wi, b_wi, W_we, b_we, wsW);

    hyperconv<<<256, 512, 0, stream>>>(
        x, wsW, conv_bias, h, index, W_bp, b_bp, W_bi, b_bi, out);
}

// Round 5
// 329.814 us; speedup vs baseline: 1.3315x; 1.0535x over previous
//
#include <hip/hip_runtime.h>
#include <hip/hip_bf16.h>

typedef short  short8  __attribute__((ext_vector_type(8)));
typedef float  f32x16  __attribute__((ext_vector_type(16)));
typedef unsigned short ushort_t;

#define B_    8
#define CIN_  64
#define COUT_ 64
#define MID_  64
#define HH    256
#define WW    256
#define NP_   4
#define NL_   5

#define TR 8              // output rows per block strip
#define TC 32             // output cols per tile
#define NJT 8             // 8*32 = 256 exact
#define SR 10             // slab rows (TR + 2 halo)
#define SCC 34            // slab cols (TC + 2 halo)
#define SLAB_U32 (SR*8*SCC*4)   // 10880 u32 = 43520 B
#define W_SHORTS (9*8*COUT_*8)  // 36864 shorts = 73728 B
#define NSTG 22                 // ceil(10880/512)

// ---------------- Kernel 1: hypernet -> combined bf16 weights ----------------
// wsW layout: [b][khkw][ci>>3][co][ci&7] shorts (verified)
__global__ __launch_bounds__(256)
void build_weights(const float* __restrict__ h, const float* __restrict__ index,
                   const float* __restrict__ conv_weight,
                   const float* __restrict__ W_wp, const float* __restrict__ b_wp,
                   const float* __restrict__ W_wi, const float* __restrict__ b_wi,
                   const float* __restrict__ W_we, const float* __restrict__ b_we,
                   ushort_t* __restrict__ wsW) {
    const int bb  = blockIdx.x / 9;       // batch
    const int ch  = blockIdx.x - bb * 9;  // o9 chunk of 64
    const int tid = threadIdx.x;

    __shared__ float pre_s[64 * 66];      // padded stride 66
    __shared__ float chunk_s[64 * 64];    // W_we chunk: 64 o9 x 64 mid

    float hv[NP_], iv[NL_];
#pragma unroll
    for (int p = 0; p < NP_; ++p) hv[p] = h[bb * NP_ + p];
#pragma unroll
    for (int l = 0; l < NL_; ++l) iv[l] = index[l];

#pragma unroll
    for (int k = 0; k < 16; ++k) {
        const int m = tid + k * 256;
        float a = b_wp[m] + b_wi[m];
#pragma unroll
        for (int p = 0; p < NP_; ++p) a += hv[p] * W_wp[m * NP_ + p];
#pragma unroll
        for (int l = 0; l < NL_; ++l) a += iv[l] * W_wi[m * NL_ + l];
        pre_s[(m >> 6) * 66 + (m & 63)] = a;
    }
#pragma unroll
    for (int k = 0; k < 16; ++k) {
        const int f = tid + k * 256;
        chunk_s[f] = W_we[ch * 4096 + f];
    }
    __syncthreads();

    const int ci = tid & 63;
    const int g  = tid >> 6;   // 0..3, uniform per wave -> chunk reads broadcast
    float acc[16];
#pragma unroll
    for (int u = 0; u < 16; ++u) acc[u] = 0.f;

#pragma unroll
    for (int mid = 0; mid < 64; mid += 2) {
        const float2 pv = *(const float2*)&pre_s[ci * 66 + mid];
#pragma unroll
        for (int u = 0; u < 16; ++u) {
            const float2 wv = *(const float2*)&chunk_s[(g + 4 * u) * 64 + mid];
            acc[u] += pv.x * wv.x + pv.y * wv.y;
        }
    }

#pragma unroll
    for (int u = 0; u < 16; ++u) {
        const int o9 = ch * 64 + g + 4 * u;
        const int co = o9 / 9;
        const int r  = o9 - co * 9;
        const float val = acc[u] + b_we[o9] + conv_weight[(co * CIN_ + ci) * 9 + r];
        __hip_bfloat16 hb = __float2bfloat16(val);
        ushort_t bits; __builtin_memcpy(&bits, &hb, 2);
        wsW[(((bb * 9 + r) * 8 + (ci >> 3)) * COUT_ + co) * 8 + (ci & 7)] = bits;
    }
}

// ---------------- Kernel 2: MFMA implicit-GEMM conv ----------------
// Slab layout (u32, each = bf16 ci-pair): [buf 2][r 10][g 8][c 34][p 4], ci = g*8+2p
// Round-0 verified staging (convert-at-load). Double-buffered slab + ONE barrier
// per iteration -> waves may skew up to one iteration, overlapping one wave's
// HBM drain with another wave's MFMA phase.
__device__ __forceinline__ void load_tile(const float* __restrict__ xb, int i0, int j0,
                                          int tid, unsigned (&vals)[NSTG]) {
#pragma unroll
    for (int k = 0; k < NSTG; ++k) {
        const int s = tid + k * 512;
        unsigned v = 0u;
        if (s < SLAB_U32) {
            const int p  = s & 3;
            const int t2 = s >> 2;
            const int c  = t2 % SCC;
            const int t3 = t2 / SCC;      // r*8 + g
            const int g  = t3 & 7;
            const int r  = t3 >> 3;
            const int gr = i0 - 1 + r;
            const int gc = j0 - 1 + c;
            const int ci = g * 8 + p * 2;
            const bool ok = ((unsigned)gr < (unsigned)HH) && ((unsigned)gc < (unsigned)WW);
            const float* px = xb + ci * (HH * WW) + (ok ? (gr * WW + gc) : 0);
            float f0 = px[0];
            float f1 = px[HH * WW];
            if (!ok) { f0 = 0.f; f1 = 0.f; }
            const __hip_bfloat162 h2 = __float22bfloat162_rn(make_float2(f0, f1));
            __builtin_memcpy(&v, &h2, 4);
        }
        vals[k] = v;
    }
}

__global__ __launch_bounds__(512, 2)
void hyperconv(const float* __restrict__ x, const ushort_t* __restrict__ wsW,
               const float* __restrict__ conv_bias,
               const float* __restrict__ h, const float* __restrict__ index,
               const float* __restrict__ W_bp, const float* __restrict__ b_bp,
               const float* __restrict__ W_bi, const float* __restrict__ b_bi,
               float* __restrict__ out) {
    __shared__ __align__(16) ushort_t Wl[W_SHORTS];      // 73728 B
    __shared__ __align__(16) unsigned Slab[2][SLAB_U32]; // 87040 B
    __shared__ float biasl[COUT_];
    // total 161,024 B <= 163,840 B -> 1 block/CU (intentional)

    const int tid   = threadIdx.x;
    const int bb    = blockIdx.x >> 5;
    const int strip = blockIdx.x & 31;
    const int i0    = strip * TR;
    const float* xb = x + bb * CIN_ * HH * WW;

    // prefetch tile 0 into regs first (latency hidden under Wl/bias setup)
    unsigned vals[NSTG];
    load_tile(xb, i0, 0, tid, vals);

    // stage weights (L2/L3-resident, coalesced 16B)
    {
        const uint4* src = (const uint4*)(wsW + bb * W_SHORTS);
        uint4* dst = (uint4*)Wl;
#pragma unroll
        for (int i = 0; i < (W_SHORTS / 8) / 512; ++i)   // 9 exact
            dst[tid + i * 512] = src[tid + i * 512];
    }
    // per-sample bias
    if (tid < COUT_) {
        const int co = tid;
        float a = conv_bias[co] + b_bp[co] + b_bi[co];
#pragma unroll
        for (int p = 0; p < NP_; ++p) a += h[bb * NP_ + p] * W_bp[co * NP_ + p];
#pragma unroll
        for (int l = 0; l < NL_; ++l) a += index[l] * W_bi[co * NL_ + l];
        biasl[co] = a;
    }

    const int lane = tid & 63;
    const int wv   = tid >> 6;     // 0..7 -> output row within strip
    const int n    = lane & 31;    // output col within tile / co for A
    const int hl   = lane >> 5;    // k-half

    for (int jt = 0; jt < NJT; ++jt) {
        // write current tile regs -> slab[jt&1].
        // Safe without a preceding barrier: last readers of this buffer were at
        // iter jt-2, and the iter jt-1 barrier is between then and now.
        unsigned* sb = Slab[jt & 1];
#pragma unroll
        for (int k = 0; k < NSTG; ++k) {
            const int s = tid + k * 512;
            if (s < SLAB_U32) sb[s] = vals[k];
        }
        // prefetch next tile (convert-at-load; drains this wave's loads here,
        // overlapping other waves' MFMA phase thanks to single-barrier skew)
        if (jt + 1 < NJT) load_tile(xb, i0, (jt + 1) * TC, tid, vals);

        // own LDS writes committed, then the ONE barrier: slab visible.
        asm volatile("s_waitcnt lgkmcnt(0)" ::: "memory");
        __builtin_amdgcn_s_barrier();

        f32x16 a0 = {}, a1 = {};
        const ushort_t* sl = (const ushort_t*)sb;
#pragma unroll
        for (int kh = 0; kh < 3; ++kh)
#pragma unroll
            for (int kw = 0; kw < 3; ++kw) {
                const int khkw = kh * 3 + kw;
#pragma unroll
                for (int kk = 0; kk < 4; ++kk) {
                    const int gA = khkw * 8 + 2 * kk + hl;
                    const short8 A0 = *(const short8*)&Wl[(gA * 64 + n) * 8];
                    const short8 A1 = *(const short8*)&Wl[(gA * 64 + n + 32) * 8];
                    const int gB = ((wv + kh) * 8 + 2 * kk + hl) * SCC + (n + kw);
                    const short8 Bf = *(const short8*)&sl[gB * 8];
                    a0 = __builtin_amdgcn_mfma_f32_32x32x16_bf16(A0, Bf, a0, 0, 0, 0);
                    a1 = __builtin_amdgcn_mfma_f32_32x32x16_bf16(A1, Bf, a1, 0, 0, 0);
                }
            }

        // epilogue: fully line-aligned stores
        const int j0 = jt * TC;
        float* op = out + (size_t)(bb * COUT_) * (HH * WW) + (i0 + wv) * WW + j0 + n;
#pragma unroll
        for (int r = 0; r < 16; ++r) {
            const int co = (r & 3) + 8 * (r >> 2) + 4 * hl;
            op[co * (HH * WW)] = a0[r] + biasl[co];
        }
#pragma unroll
        for (int r = 0; r < 16; ++r) {
            const int co = (r & 3) + 8 * (r >> 2) + 4 * hl + 32;
            op[co * (HH * WW)] = a1[r] + biasl[co];
        }
    }
}

extern "C" void kernel_launch(void* const* d_in, const int* in_sizes, int n_in,
                              void* d_out, int out_size, void* d_ws, size_t ws_size,
                              hipStream_t stream) {
    const float* x           = (const float*)d_in[0];
    const float* h           = (const float*)d_in[1];
    const float* index       = (const float*)d_in[2];
    const float* conv_weight = (const float*)d_in[3];
    const float* conv_bias   = (const float*)d_in[4];
    const float* W_wp        = (const float*)d_in[5];
    const float* b_wp        = (const float*)d_in[6];
    const float* W_wi        = (const float*)d_in[7];
    const float* b_wi        = (const float*)d_in[8];
    const float* W_we        = (const float*)d_in[9];
    const float* b_we        = (const float*)d_in[10];
    const float* W_bp        = (const float*)d_in[11];
    const float* b_bp        = (const float*)d_in[12];
    const float* W_bi        = (const float*)d_in[13];
    const float* b_bi        = (const float*)d_in[14];

    float* out = (float*)d_out;
    ushort_t* wsW = (ushort_t*)d_ws;   // 8 * 36864 * 2 = 589824 B

    build_weights<<<72, 256, 0, stream>>>(
        h, index, conv_weight, W_wp, b_wp, W_wi, b_wi, W_we, b_we, wsW);

    hyperconv<<<256, 512, 0, stream>>>(
        x, wsW, conv_bias, h, index, W_bp, b_bp, W_bi, b_bi, out);
}